// Round 7
// baseline (389.983 us; speedup 1.0000x reference)
//
#include <hip/hip_runtime.h>
#include <hip/hip_bf16.h>

#define SS 2048
#define DD 128
#define KT 64
#define NT (SS / KT)

typedef float floatx4 __attribute__((ext_vector_type(4)));
typedef __bf16 bf16x8 __attribute__((ext_vector_type(8)));
typedef unsigned short u16x4 __attribute__((ext_vector_type(4)));
typedef unsigned short u16x8 __attribute__((ext_vector_type(8)));

// ws layout (bytes): Khi [16*2048*128 bf16] @ 0, Klo @ 8388608, Vw @ 16777216.
#define KHI_OFF 0
#define KLO_OFF 8388608
#define VW_OFF  16777216
#define WS_NEED 25165824
#define KJOB    (1 << 19)       // K jobs: 16b*32kt*4ds*4g*64lane
#define BSTRIDE 262144u         // per-batch u16 stride (SS*DD)

__device__ __forceinline__ int kcol_perm(int d) {
    return ((d >> 5) << 5) | (((d & 15) >> 2) << 3) | (((d >> 4) & 1) << 2) | (d & 3);
}

__device__ __forceinline__ unsigned short bfbits(float x) {
    __bf16 h = (__bf16)x;
    return __builtin_bit_cast(unsigned short, h);
}

// ---------------------------------------------------------------------------
// Pre-pass: split K into bf16 hi/lo and transpose V to bf16, both stored in
// MFMA-fragment order so the attention kernel's operand reads are 1-KB
// contiguous wave loads. Element maps bit-identical to R4/R5-verified LDS
// images (audited per-element; R6 bug was only the consumer batch stride).
// ---------------------------------------------------------------------------
__global__ __launch_bounds__(256)
void prepack_kernel(const float* __restrict__ K, const float* __restrict__ V,
                    unsigned short* __restrict__ khi, unsigned short* __restrict__ klo,
                    unsigned short* __restrict__ vw) {
    const int tid = blockIdx.x * 256 + threadIdx.x;
    if (tid < KJOB) {
        // K job: thread = (b,kt,ds,g,lane); writes khi/klo[tid*8 .. +7]
        //   = u16 index b*262144 + kt*8192 + ds*2048 + g*512 + lane*8.
        const int lane = tid & 63, g = (tid >> 6) & 3, ds = (tid >> 8) & 3;
        const int kt = (tid >> 10) & 31, b = tid >> 15;
        const int lq = lane & 15, qg = lane >> 4;
        const int key = kt * 64 + g * 16 + lq;
        const int d0  = 32 * ds + 4 * qg;
        const float* src = K + ((size_t)(b * SS + key)) * DD + d0;
        float4 a = *(const float4*)src;
        float4 c = *(const float4*)(src + 16);
        float xs[8] = {a.x, a.y, a.z, a.w, c.x, c.y, c.z, c.w};
        u16x8 hh, ll;
#pragma unroll
        for (int j = 0; j < 8; ++j) {
            __bf16 hb = (__bf16)xs[j];
            __bf16 lb = (__bf16)(xs[j] - (float)hb);
            hh[j] = __builtin_bit_cast(unsigned short, hb);
            ll[j] = __builtin_bit_cast(unsigned short, lb);
        }
        *(u16x8*)&khi[(size_t)tid * 8] = hh;
        *(u16x8*)&klo[(size_t)tid * 8] = ll;
    } else {
        // V job: thread = (b,kt,half,qg,d); writes one 16B fragment slot.
        const int tv = tid - KJOB;
        const int d = tv & 127, qg = (tv >> 7) & 3, half = (tv >> 9) & 1;
        const int kt = (tv >> 10) & 31, b = tv >> 15;
        u16x8 vv;
#pragma unroll
        for (int j = 0; j < 8; ++j) {
            const int key = kt * 64 + 32 * half + 4 * qg + 16 * (j >> 2) + (j & 3);
            vv[j] = bfbits(V[((size_t)(b * SS + key)) * DD + d]);
        }
        const int df = d >> 4, lq = d & 15;
        const size_t slot = ((((size_t)(b * 32 + kt) * 2 + half) * 8 + df) * 16 + lq) * 4 + qg;
        *(u16x8*)&vw[slot * 8] = vv;
    }
}

// ---------------------------------------------------------------------------
// Global-direct attention: no LDS, no barriers. 512 blocks x 4 waves,
// 16 q-rows/wave -> 2 waves/SIMD for latency hiding. Operand fragments load
// straight from the prepacked ws arrays (L2-served).
// ---------------------------------------------------------------------------
__global__ __launch_bounds__(256, 2)
void attn_gd_kernel(const float* __restrict__ Q, const float* __restrict__ Sc,
                    const unsigned short* __restrict__ khi,
                    const unsigned short* __restrict__ klo,
                    const unsigned short* __restrict__ vw,
                    float* __restrict__ Out) {
    const int t    = threadIdx.x;
    const int w    = t >> 6;
    const int lane = t & 63;
    const int lq   = lane & 15;
    const int qg   = lane >> 4;

    // XCD-bijective swizzle: 512 blocks = 8 XCDs x 64; each XCD owns 2 batches.
    const int p     = blockIdx.x;
    const int wid   = ((p & 7) << 6) + (p >> 3);
    const int batch = wid >> 5;
    const int q0    = (wid & 31) << 6;

    // ---- Q fragments (hi/lo split), register-resident -----------------------
    const int qrow = q0 + (w << 4) + lq;
    const float* Qr = Q + ((size_t)batch * SS + qrow) * DD;
    bf16x8 qh[4], ql[4];
#pragma unroll
    for (int ds = 0; ds < 4; ++ds) {
#pragma unroll
        for (int h = 0; h < 2; ++h) {
            float4 qv = *(const float4*)(Qr + (qg << 2) + (h << 4) + (ds << 5));
            float xs[4] = {qv.x, qv.y, qv.z, qv.w};
#pragma unroll
            for (int e = 0; e < 4; ++e) {
                __bf16 hb = (__bf16)xs[e];
                __bf16 lb = (__bf16)(xs[e] - (float)hb);
                qh[ds][h * 4 + e] = hb;
                ql[ds][h * 4 + e] = lb;
            }
        }
    }

    const float* ScRow = Sc + (size_t)qrow * SS;

    floatx4 O[8];
#pragma unroll
    for (int i = 0; i < 8; ++i) O[i] = (floatx4){0.f, 0.f, 0.f, 0.f};
    float m_run = -INFINITY, l_run = 0.f;

    // Fragment base indices (u16 units). R6 FIX: batch stride is BSTRIDE
    // (=SS*DD u16), not the fragment-count miscount.
    const unsigned kfrag0 = (unsigned)batch * BSTRIDE + (unsigned)lane * 8;
    const unsigned vfrag0 = (unsigned)batch * BSTRIDE + (unsigned)lq * 32 + (unsigned)qg * 8;

    for (int kt = 0; kt < NT; ++kt) {
        const int kbase = kt << 6;
        const unsigned kb = kfrag0 + (unsigned)kt * 8192;
        const unsigned vb = vfrag0 + (unsigned)kt * 8192;

        // ---- swapped QK^T: S^T tiles, split-bf16 (hh + hl + lh) -------------
        floatx4 st[4];
#pragma unroll
        for (int g = 0; g < 4; ++g) st[g] = (floatx4){0.f, 0.f, 0.f, 0.f};
        __builtin_amdgcn_s_setprio(1);
#pragma unroll
        for (int ds = 0; ds < 4; ++ds) {
#pragma unroll
            for (int g = 0; g < 4; ++g) {
                const unsigned idx = kb + (unsigned)((ds * 4 + g) * 512);
                bf16x8 kh = *(const bf16x8*)&khi[idx];
                bf16x8 kl = *(const bf16x8*)&klo[idx];
                st[g] = __builtin_amdgcn_mfma_f32_16x16x32_bf16(kh, qh[ds], st[g], 0, 0, 0);
                st[g] = __builtin_amdgcn_mfma_f32_16x16x32_bf16(kh, ql[ds], st[g], 0, 0, 0);
                st[g] = __builtin_amdgcn_mfma_f32_16x16x32_bf16(kl, qh[ds], st[g], 0, 0, 0);
            }
        }
        __builtin_amdgcn_s_setprio(0);

        // ---- elementwise scale + online softmax -----------------------------
        const float* sr = ScRow + kbase;
        float4 sc0 = *(const float4*)(sr + (qg << 2));
        float4 sc1 = *(const float4*)(sr + 16 + (qg << 2));
        float4 sc2 = *(const float4*)(sr + 32 + (qg << 2));
        float4 sc3 = *(const float4*)(sr + 48 + (qg << 2));
        float sv[16];
        sv[0]  = st[0][0] * sc0.x; sv[1]  = st[0][1] * sc0.y;
        sv[2]  = st[0][2] * sc0.z; sv[3]  = st[0][3] * sc0.w;
        sv[4]  = st[1][0] * sc1.x; sv[5]  = st[1][1] * sc1.y;
        sv[6]  = st[1][2] * sc1.z; sv[7]  = st[1][3] * sc1.w;
        sv[8]  = st[2][0] * sc2.x; sv[9]  = st[2][1] * sc2.y;
        sv[10] = st[2][2] * sc2.z; sv[11] = st[2][3] * sc2.w;
        sv[12] = st[3][0] * sc3.x; sv[13] = st[3][1] * sc3.y;
        sv[14] = st[3][2] * sc3.z; sv[15] = st[3][3] * sc3.w;

        float tm = fmaxf(fmaxf(fmaxf(sv[0], sv[1]), fmaxf(sv[2], sv[3])),
                         fmaxf(fmaxf(sv[4], sv[5]), fmaxf(sv[6], sv[7])));
        float tm2 = fmaxf(fmaxf(fmaxf(sv[8], sv[9]), fmaxf(sv[10], sv[11])),
                          fmaxf(fmaxf(sv[12], sv[13]), fmaxf(sv[14], sv[15])));
        tm = fmaxf(tm, tm2);
        tm = fmaxf(tm, __shfl_xor(tm, 16));
        tm = fmaxf(tm, __shfl_xor(tm, 32));
        float mnew  = fmaxf(m_run, tm);
        float alpha = __expf(m_run - mnew);
        m_run = mnew;

        float psum = 0.f;
        bf16x8 pa0, pa1;
#pragma unroll
        for (int e = 0; e < 4; ++e) {
            float p0 = __expf(sv[e]      - mnew);
            float p1 = __expf(sv[4 + e]  - mnew);
            float p2 = __expf(sv[8 + e]  - mnew);
            float p3 = __expf(sv[12 + e] - mnew);
            psum += (p0 + p1) + (p2 + p3);
            pa0[e] = (__bf16)p0; pa0[4 + e] = (__bf16)p1;
            pa1[e] = (__bf16)p2; pa1[4 + e] = (__bf16)p3;
        }
        psum += __shfl_xor(psum, 16);
        psum += __shfl_xor(psum, 32);
        l_run = l_run * alpha + psum;

        float ar0 = __shfl(alpha, (qg << 2) + 0);
        float ar1 = __shfl(alpha, (qg << 2) + 1);
        float ar2 = __shfl(alpha, (qg << 2) + 2);
        float ar3 = __shfl(alpha, (qg << 2) + 3);
#pragma unroll
        for (int df = 0; df < 8; ++df) {
            O[df][0] *= ar0; O[df][1] *= ar1; O[df][2] *= ar2; O[df][3] *= ar3;
        }

        // ---- PV: A = P (from S^T accum layout), B = V fragments (global) ----
        __builtin_amdgcn_s_setprio(1);
#pragma unroll
        for (int df = 0; df < 8; ++df) {
            bf16x8 vf0 = *(const bf16x8*)&vw[vb + (unsigned)(df * 512)];
            bf16x8 vf1 = *(const bf16x8*)&vw[vb + 4096u + (unsigned)(df * 512)];
            O[df] = __builtin_amdgcn_mfma_f32_16x16x32_bf16(pa0, vf0, O[df], 0, 0, 0);
            O[df] = __builtin_amdgcn_mfma_f32_16x16x32_bf16(pa1, vf1, O[df], 0, 0, 0);
        }
        __builtin_amdgcn_s_setprio(0);
    }

    // ---- epilogue -----------------------------------------------------------
    float inv0 = 1.f / __shfl(l_run, (qg << 2) + 0);
    float inv1 = 1.f / __shfl(l_run, (qg << 2) + 1);
    float inv2 = 1.f / __shfl(l_run, (qg << 2) + 2);
    float inv3 = 1.f / __shfl(l_run, (qg << 2) + 3);
    const size_t obase = ((size_t)batch * SS + (size_t)(q0 + (w << 4))) * DD;
#pragma unroll
    for (int df = 0; df < 8; ++df) {
        int d = lq + (df << 4);
        Out[obase + (size_t)((qg << 2) + 0) * DD + d] = O[df][0] * inv0;
        Out[obase + (size_t)((qg << 2) + 1) * DD + d] = O[df][1] * inv1;
        Out[obase + (size_t)((qg << 2) + 2) * DD + d] = O[df][2] * inv2;
        Out[obase + (size_t)((qg << 2) + 3) * DD + d] = O[df][3] * inv3;
    }
}

// ---------------------------------------------------------------------------
// Fallback (R5 kernel, verified): used only if ws_size < WS_NEED.
// ---------------------------------------------------------------------------
__global__ __launch_bounds__(256, 1)
void attn_scaled_kernel(const float* __restrict__ Q, const float* __restrict__ K,
                        const float* __restrict__ V, const float* __restrict__ Sc,
                        float* __restrict__ Out) {
    __shared__ __align__(16) unsigned short Khi[KT * DD];
    __shared__ __align__(16) unsigned short Klo[KT * DD];
    __shared__ __align__(16) unsigned short Vt[DD * KT];

    const int t    = threadIdx.x;
    const int w    = t >> 6;
    const int lane = t & 63;
    const int lq   = lane & 15;
    const int qg   = lane >> 4;

    const int p     = blockIdx.x;
    const int wid   = ((p & 7) << 5) + (p >> 3);
    const int batch = wid >> 4;
    const int q0    = (wid & 15) << 7;

    const float* Qb = Q + (size_t)batch * SS * DD;
    const float* Kb = K + (size_t)batch * SS * DD;
    const float* Vb = V + (size_t)batch * SS * DD;

    const int srow = t >> 5;
    const int c4   = (t & 31) << 2;
    const int kw0  = srow * 128 + (kcol_perm(c4) ^ ((srow & 7) << 3));
    const float* Kp = Kb + (size_t)srow * DD + c4;

    const int vd   = ((w & 1) << 6) + lane;
    const int vkv  = w >> 1;
    const int vswz = (vd & 7) << 3;
    const float* Vp = Vb + vd;

#define STAGE_K(I, KV) do {                                           \
        float ks_[4] = {(KV).x, (KV).y, (KV).z, (KV).w};              \
        u16x4 hh_, ll_;                                               \
        _Pragma("unroll")                                             \
        for (int e_ = 0; e_ < 4; ++e_) {                              \
            __bf16 hb_ = (__bf16)ks_[e_];                             \
            __bf16 lb_ = (__bf16)(ks_[e_] - (float)hb_);              \
            hh_[e_] = __builtin_bit_cast(unsigned short, hb_);        \
            ll_[e_] = __builtin_bit_cast(unsigned short, lb_);        \
        }                                                             \
        *(u16x4*)&Khi[kw0 + 1024 * (I)] = hh_;                        \
        *(u16x4*)&Klo[kw0 + 1024 * (I)] = ll_;                        \
    } while (0)

#define STAGE_V(I, VPI) do {                                          \
        u16x8 vv_;                                                    \
        _Pragma("unroll")                                             \
        for (int e_ = 0; e_ < 8; ++e_) vv_[e_] = bfbits((VPI)[e_]);   \
        *(u16x8*)&Vt[((vd << 6) + (vkv << 5) + ((I) << 3)) ^ vswz] = vv_; \
    } while (0)

#define LOAD_V(I, VPI, BASE) do {                                     \
        _Pragma("unroll")                                             \
        for (int h_ = 0; h_ < 2; ++h_)                                \
            _Pragma("unroll")                                         \
            for (int j_ = 0; j_ < 4; ++j_)                            \
                (VPI)[h_ * 4 + j_] =                                  \
                    Vp[(BASE) + (size_t)((vkv << 5) + ((I) << 2) + (h_ << 4) + j_) * DD]; \
    } while (0)

    const int qrow0 = q0 + (w << 5) + lq;
    bf16x8 qh[2][4], ql[2][4];
#pragma unroll
    for (int h2 = 0; h2 < 2; ++h2) {
        const float* Qr = Qb + (size_t)(qrow0 + 16 * h2) * DD;
#pragma unroll
        for (int ds = 0; ds < 4; ++ds) {
#pragma unroll
            for (int h = 0; h < 2; ++h) {
                float4 qv = *(const float4*)(Qr + (qg << 2) + (h << 4) + (ds << 5));
                float xs[4] = {qv.x, qv.y, qv.z, qv.w};
#pragma unroll
                for (int e = 0; e < 4; ++e) {
                    __bf16 hb = (__bf16)xs[e];
                    __bf16 lb = (__bf16)(xs[e] - (float)hb);
                    qh[h2][ds][h * 4 + e] = hb;
                    ql[h2][ds][h * 4 + e] = lb;
                }
            }
        }
    }

    const float* ScRow0 = Sc + (size_t)qrow0 * SS;

    float4 scur[2][4];
    {
        float4 kn[8];
        float  vp[4][8];
#pragma unroll
        for (int i = 0; i < 8; ++i) kn[i] = *(const float4*)(Kp + (size_t)(8 * i) * DD);
#pragma unroll
        for (int i = 0; i < 4; ++i) LOAD_V(i, vp[i], 0);
#pragma unroll
        for (int h2 = 0; h2 < 2; ++h2)
#pragma unroll
            for (int g = 0; g < 4; ++g)
                scur[h2][g] = *(const float4*)(ScRow0 + (size_t)(h2 * 16) * SS + g * 16 + (qg << 2));
#pragma unroll
        for (int i = 0; i < 8; ++i) STAGE_K(i, kn[i]);
#pragma unroll
        for (int i = 0; i < 4; ++i) STAGE_V(i, vp[i]);
    }
    __syncthreads();

    floatx4 O[2][8];
#pragma unroll
    for (int h2 = 0; h2 < 2; ++h2)
#pragma unroll
        for (int i = 0; i < 8; ++i) O[h2][i] = (floatx4){0.f, 0.f, 0.f, 0.f};
    float m_run[2] = {-INFINITY, -INFINITY};
    float l_run[2] = {0.f, 0.f};

    for (int kt = 0; kt < NT; ++kt) {
        const int kbase = kt << 6;
        const bool pre = (kt + 1 < NT);
        float4 kn[8], scn[2][4];
        float  vp[4][8];
        if (pre) {
            const size_t off = (size_t)(kbase + KT) * DD;
#pragma unroll
            for (int i = 0; i < 8; ++i)
                kn[i] = *(const float4*)(Kp + off + (size_t)(8 * i) * DD);
#pragma unroll
            for (int i = 0; i < 4; ++i) LOAD_V(i, vp[i], off);
#pragma unroll
            for (int h2 = 0; h2 < 2; ++h2)
#pragma unroll
                for (int g = 0; g < 4; ++g)
                    scn[h2][g] = *(const float4*)(ScRow0 + (size_t)(h2 * 16) * SS
                                                  + kbase + KT + g * 16 + (qg << 2));
        }

        floatx4 st[2][4];
#pragma unroll
        for (int h2 = 0; h2 < 2; ++h2)
#pragma unroll
            for (int g = 0; g < 4; ++g) st[h2][g] = (floatx4){0.f, 0.f, 0.f, 0.f};
        const int sx = (lq & 7) << 3;
        __builtin_amdgcn_s_setprio(1);
#pragma unroll
        for (int ds = 0; ds < 4; ++ds) {
            const int cc = (ds << 5) + (qg << 3);
#pragma unroll
            for (int g = 0; g < 4; ++g) {
                const int b = ((g * 16 + lq) * 128 + cc) ^ sx;
                bf16x8 kh = *(const bf16x8*)&Khi[b];
                bf16x8 kl = *(const bf16x8*)&Klo[b];
#pragma unroll
                for (int h2 = 0; h2 < 2; ++h2) {
                    st[h2][g] = __builtin_amdgcn_mfma_f32_16x16x32_bf16(kh, qh[h2][ds], st[h2][g], 0, 0, 0);
                    st[h2][g] = __builtin_amdgcn_mfma_f32_16x16x32_bf16(kh, ql[h2][ds], st[h2][g], 0, 0, 0);
                    st[h2][g] = __builtin_amdgcn_mfma_f32_16x16x32_bf16(kl, qh[h2][ds], st[h2][g], 0, 0, 0);
                }
            }
        }
        __builtin_amdgcn_s_setprio(0);

        bf16x8 pa[2][2];
#pragma unroll
        for (int h2 = 0; h2 < 2; ++h2) {
            float sv[16];
#pragma unroll
            for (int g = 0; g < 4; ++g) {
                sv[g * 4 + 0] = st[h2][g][0] * scur[h2][g].x;
                sv[g * 4 + 1] = st[h2][g][1] * scur[h2][g].y;
                sv[g * 4 + 2] = st[h2][g][2] * scur[h2][g].z;
                sv[g * 4 + 3] = st[h2][g][3] * scur[h2][g].w;
            }
            float tm = fmaxf(fmaxf(fmaxf(sv[0], sv[1]), fmaxf(sv[2], sv[3])),
                             fmaxf(fmaxf(sv[4], sv[5]), fmaxf(sv[6], sv[7])));
            float tm2 = fmaxf(fmaxf(fmaxf(sv[8], sv[9]), fmaxf(sv[10], sv[11])),
                              fmaxf(fmaxf(sv[12], sv[13]), fmaxf(sv[14], sv[15])));
            tm = fmaxf(tm, tm2);
            tm = fmaxf(tm, __shfl_xor(tm, 16));
            tm = fmaxf(tm, __shfl_xor(tm, 32));
            float mnew  = fmaxf(m_run[h2], tm);
            float alpha = __expf(m_run[h2] - mnew);
            m_run[h2] = mnew;

            float psum = 0.f;
#pragma unroll
            for (int e = 0; e < 4; ++e) {
                float p0 = __expf(sv[e]      - mnew);
                float p1 = __expf(sv[4 + e]  - mnew);
                float p2 = __expf(sv[8 + e]  - mnew);
                float p3 = __expf(sv[12 + e] - mnew);
                psum += (p0 + p1) + (p2 + p3);
                pa[h2][0][e] = (__bf16)p0; pa[h2][0][4 + e] = (__bf16)p1;
                pa[h2][1][e] = (__bf16)p2; pa[h2][1][4 + e] = (__bf16)p3;
            }
            psum += __shfl_xor(psum, 16);
            psum += __shfl_xor(psum, 32);
            l_run[h2] = l_run[h2] * alpha + psum;

            float ar0 = __shfl(alpha, (qg << 2) + 0);
            float ar1 = __shfl(alpha, (qg << 2) + 1);
            float ar2 = __shfl(alpha, (qg << 2) + 2);
            float ar3 = __shfl(alpha, (qg << 2) + 3);
#pragma unroll
            for (int df = 0; df < 8; ++df) {
                O[h2][df][0] *= ar0; O[h2][df][1] *= ar1;
                O[h2][df][2] *= ar2; O[h2][df][3] *= ar3;
            }
        }

        __builtin_amdgcn_s_setprio(1);
#pragma unroll
        for (int df = 0; df < 8; ++df) {
            const int d   = lq + (df << 4);
            const int vb0 = (((d << 6) +      (qg << 3)) ^ sx);
            const int vb1 = (((d << 6) + 32 + (qg << 3)) ^ sx);
            bf16x8 vf0 = *(const bf16x8*)&Vt[vb0];
            bf16x8 vf1 = *(const bf16x8*)&Vt[vb1];
#pragma unroll
            for (int h2 = 0; h2 < 2; ++h2) {
                O[h2][df] = __builtin_amdgcn_mfma_f32_16x16x32_bf16(pa[h2][0], vf0, O[h2][df], 0, 0, 0);
                O[h2][df] = __builtin_amdgcn_mfma_f32_16x16x32_bf16(pa[h2][1], vf1, O[h2][df], 0, 0, 0);
            }
        }
        __builtin_amdgcn_s_setprio(0);

        if (pre) {
            __syncthreads();
#pragma unroll
            for (int i = 0; i < 8; ++i) STAGE_K(i, kn[i]);
#pragma unroll
            for (int i = 0; i < 4; ++i) STAGE_V(i, vp[i]);
#pragma unroll
            for (int h2 = 0; h2 < 2; ++h2)
#pragma unroll
                for (int g = 0; g < 4; ++g) scur[h2][g] = scn[h2][g];
            __syncthreads();
        }
    }

#pragma unroll
    for (int h2 = 0; h2 < 2; ++h2) {
        float inv0 = 1.f / __shfl(l_run[h2], (qg << 2) + 0);
        float inv1 = 1.f / __shfl(l_run[h2], (qg << 2) + 1);
        float inv2 = 1.f / __shfl(l_run[h2], (qg << 2) + 2);
        float inv3 = 1.f / __shfl(l_run[h2], (qg << 2) + 3);
        const size_t obase = ((size_t)batch * SS + (size_t)(q0 + (w << 5) + 16 * h2)) * DD;
#pragma unroll
        for (int df = 0; df < 8; ++df) {
            int d = lq + (df << 4);
            Out[obase + (size_t)((qg << 2) + 0) * DD + d] = O[h2][df][0] * inv0;
            Out[obase + (size_t)((qg << 2) + 1) * DD + d] = O[h2][df][1] * inv1;
            Out[obase + (size_t)((qg << 2) + 2) * DD + d] = O[h2][df][2] * inv2;
            Out[obase + (size_t)((qg << 2) + 3) * DD + d] = O[h2][df][3] * inv3;
        }
    }
#undef STAGE_K
#undef STAGE_V
#undef LOAD_V
}

extern "C" void kernel_launch(void* const* d_in, const int* in_sizes, int n_in,
                              void* d_out, int out_size, void* d_ws, size_t ws_size,
                              hipStream_t stream) {
    const float* q  = (const float*)d_in[0];
    const float* k  = (const float*)d_in[1];
    const float* v  = (const float*)d_in[2];
    const float* sc = (const float*)d_in[3];
    float* out = (float*)d_out;
    if (ws_size >= (size_t)WS_NEED) {
        unsigned short* khi = (unsigned short*)((char*)d_ws + KHI_OFF);
        unsigned short* klo = (unsigned short*)((char*)d_ws + KLO_OFF);
        unsigned short* vw  = (unsigned short*)((char*)d_ws + VW_OFF);
        hipLaunchKernelGGL(prepack_kernel, dim3(4096), dim3(256), 0, stream,
                           k, v, khi, klo, vw);
        hipLaunchKernelGGL(attn_gd_kernel, dim3(512), dim3(256), 0, stream,
                           q, sc, khi, klo, vw, out);
    } else {
        hipLaunchKernelGGL(attn_scaled_kernel, dim3(256), dim3(256), 0, stream,
                           q, k, v, sc, out);
    }
}